// Round 1
// baseline (435.062 us; speedup 1.0000x reference)
//
#include <hip/hip_runtime.h>

#define NT 256
#define TOK 256

// Coalesced float4 stage of 256 rows x 45 floats (= 2880 float4) into LDS.
__device__ __forceinline__ void stage_qkv(const float* __restrict__ g, float* __restrict__ s,
                                          int base, int tid) {
    const float4* __restrict__ g4 = (const float4*)(g + (size_t)base * 45);
    float4* s4 = (float4*)s;
    #pragma unroll
    for (int it = 0; it < 12; ++it) {
        int idx = tid + it * NT;
        if (idx < 2880) s4[idx] = g4[idx];
    }
}

// dst[h][n] = (|.|) sum_d row[d*15+n] * W[h*3+d] + B[h]
template <bool ABS>
__device__ __forceinline__ void project(const float* __restrict__ s, int tid,
                                        const float* __restrict__ W, const float* __restrict__ B,
                                        float dst[3][15]) {
    float w[9], bb[3];
    #pragma unroll
    for (int i = 0; i < 9; ++i) w[i] = W[i];
    #pragma unroll
    for (int i = 0; i < 3; ++i) bb[i] = B[i];
    const float* row = s + tid * 45;   // stride 45 across lanes -> 2-way bank alias (free)
    #pragma unroll
    for (int n = 0; n < 15; ++n) {
        float x0 = row[n], x1 = row[15 + n], x2 = row[30 + n];
        #pragma unroll
        for (int h = 0; h < 3; ++h) {
            float y = fmaf(x2, w[h*3+2], fmaf(x1, w[h*3+1], fmaf(x0, w[h*3+0], bb[h])));
            dst[h][n] = ABS ? fabsf(y) : y;
        }
    }
}

__global__ __launch_bounds__(NT, 2) void mha_spatial_kernel(
    const float* __restrict__ q, const float* __restrict__ k, const float* __restrict__ v,
    const float* __restrict__ dist,
    const float* __restrict__ Wq, const float* __restrict__ bq,
    const float* __restrict__ Wk, const float* __restrict__ bk,
    const float* __restrict__ Wv, const float* __restrict__ bv,
    const float* __restrict__ Wo, const float* __restrict__ bo,
    float* __restrict__ out)
{
    __shared__ __align__(16) float stage[11520]; // 45 KB: q -> k -> v -> 5x dist chunks -> output
    __shared__ float wbuf[2070];                 // Wo (2025) + bo (45)
    const int tid = threadIdx.x;
    const int base = blockIdx.x * TOK;

    // Wo/bo into LDS (separate buffer, no phase conflict)
    for (int idx = tid; idx < 2070; idx += NT)
        wbuf[idx] = (idx < 2025) ? Wo[idx] : bo[idx - 2025];

    float a[3][15], b[3][15], vv[3][15];

    stage_qkv(q, stage, base, tid);
    __syncthreads();
    project<true>(stage, tid, Wq, bq, a);
    __syncthreads();

    stage_qkv(k, stage, base, tid);
    __syncthreads();
    project<true>(stage, tid, Wk, bk, b);
    __syncthreads();

    stage_qkv(v, stage, base, tid);
    __syncthreads();
    project<false>(stage, tid, Wv, bv, vv);
    // stage is next overwritten inside the distance loop, after its own barrier.

    // ---- softmax + P.v  (scores = a_i*b_j >= 0, so max = amax*bmax) ----
    float concat[45];   // concat[n*3+h] = out[h][n]
    #pragma unroll
    for (int h = 0; h < 3; ++h) {
        float amax = a[h][0], bmax = b[h][0];
        #pragma unroll
        for (int n = 1; n < 15; ++n) { amax = fmaxf(amax, a[h][n]); bmax = fmaxf(bmax, b[h][n]); }
        const float mm = amax * bmax;
        float Z = 0.f;
        float pv[15];
        #pragma unroll
        for (int i = 0; i < 15; ++i) pv[i] = 0.f;
        #pragma unroll
        for (int i = 0; i < 15; ++i) {
            #pragma unroll
            for (int j = 0; j < 15; ++j) {
                float t = __expf(fmaf(a[h][i], b[h][j], -mm));
                Z += t;
                pv[i] = fmaf(t, vv[h][j], pv[i]);
            }
        }
        const float rz = 1.f / Z;
        #pragma unroll
        for (int i = 0; i < 15; ++i) concat[i*3 + h] = pv[i] * rz;
    }

    // fold the 2.0 * distances factor into v
    #pragma unroll
    for (int h = 0; h < 3; ++h)
        #pragma unroll
        for (int j = 0; j < 15; ++j) vv[h][j] *= 2.f;

    // ---- distance bias: out[h][i] += sum_j 2*D[i][j]*vh[h][j], 5 chunks of 3 rows ----
    #pragma unroll
    for (int c = 0; c < 5; ++c) {
        __syncthreads();
        {
            // linear chunk index m = tok*45 + e ; global addr = (base+tok)*225 + c*45 + e
            int m = tid, tok = tid / 45, e = tid - tok * 45;
            #pragma unroll 1
            for (int it = 0; it < 45; ++it) {
                stage[m] = dist[(size_t)(base + tok) * 225 + c * 45 + e];
                m += NT; tok += 5; e += 31;            // 256 = 5*45 + 31
                if (e >= 45) { e -= 45; tok += 1; }
            }
        }
        __syncthreads();
        #pragma unroll
        for (int r = 0; r < 3; ++r) {
            #pragma unroll
            for (int j = 0; j < 15; ++j) {
                float dd = stage[tid*45 + r*15 + j];
                #pragma unroll
                for (int h = 0; h < 3; ++h)
                    concat[(c*3+r)*3 + h] = fmaf(dd, vv[h][j], concat[(c*3+r)*3 + h]);
            }
        }
    }

    __syncthreads();
    // ---- output projection: out_o = bo[o] + sum_c concat[c]*Wo[o*45+c] ----
    #pragma unroll 1
    for (int o = 0; o < 45; ++o) {       // o uniform across lanes -> wbuf reads broadcast
        float acc = wbuf[2025 + o];
        const int wb = o * 45;
        #pragma unroll
        for (int cc = 0; cc < 45; ++cc) acc = fmaf(concat[cc], wbuf[wb + cc], acc);
        stage[tid * 45 + o] = acc;
    }
    __syncthreads();
    {
        float4* g4 = (float4*)(out + (size_t)base * 45);
        const float4* s4 = (const float4*)stage;
        #pragma unroll
        for (int it = 0; it < 12; ++it) {
            int idx = tid + it * NT;
            if (idx < 2880) g4[idx] = s4[idx];
        }
    }
}

extern "C" void kernel_launch(void* const* d_in, const int* in_sizes, int n_in,
                              void* d_out, int out_size, void* d_ws, size_t ws_size,
                              hipStream_t stream) {
    const float* q  = (const float*)d_in[0];
    const float* k  = (const float*)d_in[1];
    const float* v  = (const float*)d_in[2];
    const float* ds = (const float*)d_in[3];
    const float* Wq = (const float*)d_in[5];
    const float* bq = (const float*)d_in[6];
    const float* Wk = (const float*)d_in[7];
    const float* bk = (const float*)d_in[8];
    const float* Wv = (const float*)d_in[9];
    const float* bv = (const float*)d_in[10];
    const float* Wo = (const float*)d_in[11];
    const float* bo = (const float*)d_in[12];
    float* out = (float*)d_out;

    // att_val = zeros(4096) at the tail of d_out
    hipMemsetAsync(out + (size_t)32 * 4096 * 45, 0, 4096 * sizeof(float), stream);

    mha_spatial_kernel<<<dim3(512), dim3(NT), 0, stream>>>(
        q, k, v, ds, Wq, bq, Wk, bk, Wv, bv, Wo, bo, out);
}

// Round 2
// 91.350 us; speedup vs baseline: 4.7626x; 4.7626x over previous
//
#include <hip/hip_runtime.h>

#define NT 128
#define TOK 128

// ---- async global->LDS (no VGPR round trip). size is a literal. ----
#define GL16(gp, lp) __builtin_amdgcn_global_load_lds( \
    (const __attribute__((address_space(1))) void*)(gp), \
    (__attribute__((address_space(3))) void*)(lp), 16, 0, 0)
#define GL4(gp, lp) __builtin_amdgcn_global_load_lds( \
    (const __attribute__((address_space(1))) void*)(gp), \
    (__attribute__((address_space(3))) void*)(lp), 4, 0, 0)

#define WAITVM(N) asm volatile("s_waitcnt vmcnt(" #N ")" ::: "memory")
#define BAR() do { __builtin_amdgcn_s_barrier(); __builtin_amdgcn_sched_barrier(0); } while (0)

// dst[h][n] = (|.|) sum_d row[d*15+n] * W[h*3+d] + B[h]   (row in LDS, stride-45/lane = 2-way bank, free)
template <bool ABS>
__device__ __forceinline__ void project(const float* row, const float* __restrict__ W,
                                        const float* __restrict__ Bb, float dst[3][15]) {
    float w[9], bb[3];
    #pragma unroll
    for (int i = 0; i < 9; ++i) w[i] = W[i];
    #pragma unroll
    for (int i = 0; i < 3; ++i) bb[i] = Bb[i];
    #pragma unroll
    for (int n = 0; n < 15; ++n) {
        float x0 = row[n], x1 = row[15 + n], x2 = row[30 + n];
        #pragma unroll
        for (int h = 0; h < 3; ++h) {
            float y = fmaf(x2, w[h*3+2], fmaf(x1, w[h*3+1], fmaf(x0, w[h*3+0], bb[h])));
            dst[h][n] = ABS ? fabsf(y) : y;
        }
    }
}

// Stage one 45-float/token distance chunk (5760 floats) linearly into buf.
// element m = it*128 + tid ; token = m/45, e = m%45 ; global = dptr + token*225 + e.
// Incremental index update: m += 128  =>  e += 38 (wrap 45), off += 488 / 668.
__device__ __forceinline__ void stage_dist(const float* dptr, float* buf,
                                           int off0, int e0, int wid) {
    int off = off0, e = e0;
    #pragma unroll
    for (int it = 0; it < 45; ++it) {
        GL4(dptr + off, buf + it * 128 + wid * 64);   // LDS dest: wave-uniform base + lane*4
        e += 38;
        bool wrap = (e >= 45);
        e -= wrap ? 45 : 0;
        off += wrap ? 668 : 488;   // wrap: 3*225-7 ; no wrap: 2*225+38
    }
}

template <int C>
__device__ __forceinline__ void dist_acc(const float* cur, int tid,
                                         const float vv[3][15], float concat[45]) {
    const float* row = cur + tid * 45;
    #pragma unroll
    for (int r = 0; r < 3; ++r)
        #pragma unroll
        for (int j = 0; j < 15; ++j) {
            float dd = row[r*15 + j];
            #pragma unroll
            for (int h = 0; h < 3; ++h)
                concat[(C*3 + r)*3 + h] = fmaf(dd, vv[h][j], concat[(C*3 + r)*3 + h]);
        }
}

__global__ __launch_bounds__(NT, 1) void mha_spatial_kernel(
    const float* __restrict__ q, const float* __restrict__ k, const float* __restrict__ v,
    const float* __restrict__ dist,
    const float* __restrict__ Wq, const float* __restrict__ bq,
    const float* __restrict__ Wk, const float* __restrict__ bk,
    const float* __restrict__ Wv, const float* __restrict__ bv,
    const float* __restrict__ Wo, const float* __restrict__ bo,
    float* __restrict__ out)
{
    __shared__ __align__(16) float bufA[5760];   // 22.5 KB
    __shared__ __align__(16) float bufB[5760];   // 22.5 KB
    __shared__ float wbuf[2025];                 // Wo only (bo via s_load)
    const int tid = threadIdx.x;
    const int wid = tid >> 6;
    const int base = blockIdx.x * TOK;

    // ---- prologue: issue q->bufA, k->bufB, Wo->wbuf; one full drain ----
    {
        const float* q0 = q + (size_t)base * 45;
        const float* k0 = k + (size_t)base * 45;
        #pragma unroll
        for (int it = 0; it < 12; ++it) {
            int idx = it * 128 + tid;                     // float4 index, 1440 total
            if (idx < 1440) {
                GL16(q0 + idx * 4, (float*)((float4*)bufA + it * 128 + wid * 64));
                GL16(k0 + idx * 4, (float*)((float4*)bufB + it * 128 + wid * 64));
            }
        }
        #pragma unroll
        for (int it = 0; it < 16; ++it) {
            int idx = it * 128 + tid;
            if (idx < 2025) GL4(Wo + idx, wbuf + it * 128 + wid * 64);
        }
    }
    __syncthreads();

    float a[3][15], b[3][15];
    project<true >(bufA + tid * 45, Wq, bq, a);
    project<true >(bufB + tid * 45, Wk, bk, b);
    __syncthreads();                     // all reads of bufA/bufB complete

    // ---- issue v->bufA (12 x 16B) then dist chunk0 -> bufB (45 x 4B) ----
    const int tok0 = tid / 45, e0 = tid - tok0 * 45;
    const int off0 = tok0 * 225 + e0;
    const float* dbase = dist + (size_t)base * 225;
    {
        const float* v0 = v + (size_t)base * 45;
        #pragma unroll
        for (int it = 0; it < 12; ++it) {
            int idx = it * 128 + tid;
            if (idx < 1440) GL16(v0 + idx * 4, (float*)((float4*)bufA + it * 128 + wid * 64));
        }
    }
    stage_dist(dbase + 0 * 45, bufB, off0, e0, wid);
    WAITVM(45);                          // oldest 12 (v) retired; 45 dist still in flight
    BAR();

    float vv[3][15];
    project<false>(bufA + tid * 45, Wv, bv, vv);

    // ---- softmax + PV (pure registers; overlaps chunk0 flight) ----
    // scores = a_i*b_j >= 0  =>  max = amax*bmax
    float concat[45];                    // concat[n*3+h] = out[h][n]
    #pragma unroll
    for (int h = 0; h < 3; ++h) {
        float amax = a[h][0], bmax = b[h][0];
        #pragma unroll
        for (int n = 1; n < 15; ++n) { amax = fmaxf(amax, a[h][n]); bmax = fmaxf(bmax, b[h][n]); }
        const float mm = amax * bmax;
        float Z = 0.f, pv[15];
        #pragma unroll
        for (int i = 0; i < 15; ++i) pv[i] = 0.f;
        #pragma unroll
        for (int i = 0; i < 15; ++i)
            #pragma unroll
            for (int j = 0; j < 15; ++j) {
                float t = __expf(fmaf(a[h][i], b[h][j], -mm));
                Z += t;
                pv[i] = fmaf(t, vv[h][j], pv[i]);
            }
        const float rz = 1.f / Z;
        #pragma unroll
        for (int i = 0; i < 15; ++i) concat[i*3 + h] = pv[i] * rz;
    }
    #pragma unroll
    for (int h = 0; h < 3; ++h)
        #pragma unroll
        for (int j = 0; j < 15; ++j) vv[h][j] *= 2.f;   // fold 2*distances into v

    WAITVM(0);                           // chunk0 landed in bufB
    BAR();                               // + all waves done reading bufA (v)

    // ---- distance stream, double-buffered, counted prefetch 1 deep ----
    stage_dist(dbase + 1 * 45, bufA, off0, e0, wid);
    dist_acc<0>(bufB, tid, vv, concat);
    WAITVM(0); BAR();

    stage_dist(dbase + 2 * 45, bufB, off0, e0, wid);
    dist_acc<1>(bufA, tid, vv, concat);
    WAITVM(0); BAR();

    stage_dist(dbase + 3 * 45, bufA, off0, e0, wid);
    dist_acc<2>(bufB, tid, vv, concat);
    WAITVM(0); BAR();

    stage_dist(dbase + 4 * 45, bufB, off0, e0, wid);
    dist_acc<3>(bufA, tid, vv, concat);
    WAITVM(0); BAR();

    dist_acc<4>(bufB, tid, vv, concat);
    BAR();                               // bufA reads (c3) done everywhere

    // ---- output projection: out_o = bo[o] + sum_c concat[c] * Wo[o*45+c] ----
    #pragma unroll 1
    for (int o = 0; o < 45; ++o) {       // o uniform across lanes -> wbuf broadcast reads
        float acc = 0.f;
        const int wb = o * 45;
        #pragma unroll
        for (int cc = 0; cc < 45; ++cc) acc = fmaf(concat[cc], wbuf[wb + cc], acc);
        bufA[tid * 45 + o] = acc + bo[o];
    }
    __syncthreads();
    {
        float4* o4 = (float4*)(out + (size_t)base * 45);
        #pragma unroll
        for (int it = 0; it < 12; ++it) {
            int idx = it * 128 + tid;
            if (idx < 1440) o4[idx] = ((const float4*)bufA)[idx];
        }
    }
}

extern "C" void kernel_launch(void* const* d_in, const int* in_sizes, int n_in,
                              void* d_out, int out_size, void* d_ws, size_t ws_size,
                              hipStream_t stream) {
    const float* q  = (const float*)d_in[0];
    const float* k  = (const float*)d_in[1];
    const float* v  = (const float*)d_in[2];
    const float* ds = (const float*)d_in[3];
    const float* Wq = (const float*)d_in[5];
    const float* bq = (const float*)d_in[6];
    const float* Wk = (const float*)d_in[7];
    const float* bk = (const float*)d_in[8];
    const float* Wv = (const float*)d_in[9];
    const float* bv = (const float*)d_in[10];
    const float* Wo = (const float*)d_in[11];
    const float* bo = (const float*)d_in[12];
    float* out = (float*)d_out;

    // att_val = zeros(4096) at the tail of d_out
    hipMemsetAsync(out + (size_t)32 * 4096 * 45, 0, 4096 * sizeof(float), stream);

    mha_spatial_kernel<<<dim3((32 * 4096) / TOK), dim3(NT), 0, stream>>>(
        q, k, v, ds, Wq, bq, Wk, bk, Wv, bv, Wo, bo, out);
}